// Round 12
// baseline (1066.402 us; speedup 1.0000x reference)
//
#include <hip/hip_runtime.h>
#include <hip/hip_cooperative_groups.h>
#include <math.h>

namespace cg = cooperative_groups;

#define B    128
#define NLOC 196
#define DV   512
#define EMB  512
#define HD   1024
#define VV   10000
#define TT   20
#define G4   4096   // 4*HD
#define VPAD 10112  // 79*128
#define BH   (B*HD)

typedef short bf16x8 __attribute__((ext_vector_type(8)));
typedef float f32x4  __attribute__((ext_vector_type(4)));

__device__ __forceinline__ unsigned short f2bf(float x) {
    unsigned u = __builtin_bit_cast(unsigned, x);
    unsigned r = (u + 0x7fffu + ((u >> 16) & 1u)) >> 16;
    return (unsigned short)r;
}

__device__ __forceinline__ void gload_lds16(const void* g, void* lds) {
    __builtin_amdgcn_global_load_lds(
        (const __attribute__((address_space(1))) void*)g,
        (__attribute__((address_space(3))) void*)lds, 16, 0, 0);
}

// ---------------- small kernels ----------------

__global__ void fmean_kernel(const float* __restrict__ feat, short* __restrict__ fmean_b) {
    int idx = blockIdx.x * blockDim.x + threadIdx.x;   // B*DV
    if (idx >= B * DV) return;
    int b = idx / DV, d = idx % DV;
    const float* p = feat + (size_t)b * NLOC * DV + d;
    float s = 0.f;
    for (int n = 0; n < NLOC; ++n) s += p[(size_t)n * DV];
    fmean_b[idx] = (short)f2bf(s * (1.0f / NLOC));
}

__global__ void attv_kernel(const float* __restrict__ feat, const float* __restrict__ wv,
                            const float* __restrict__ bv, float* __restrict__ attv) {
    int row  = blockIdx.x;         // B*NLOC
    int lane = threadIdx.x;        // 64
    const float* p = feat + (size_t)row * DV;
    float s = 0.f;
    for (int k = lane; k < DV; k += 64) s += p[k] * wv[k];
    for (int off = 32; off > 0; off >>= 1) s += __shfl_down(s, off);
    if (lane == 0) attv[row] = s + bv[0];
}

__global__ void alpha_kernel(const float* __restrict__ attv, float* __restrict__ alpha) {
    int b   = blockIdx.x;          // B
    int tid = threadIdx.x;         // 256
    __shared__ float red[256];
    float v = (tid < NLOC) ? attv[b * NLOC + tid] : -1e30f;
    red[tid] = v; __syncthreads();
    for (int s = 128; s > 0; s >>= 1) { if (tid < s) red[tid] = fmaxf(red[tid], red[tid + s]); __syncthreads(); }
    float m = red[0]; __syncthreads();
    float e = (tid < NLOC) ? expf(v - m) : 0.f;
    red[tid] = e; __syncthreads();
    for (int s = 128; s > 0; s >>= 1) { if (tid < s) red[tid] += red[tid + s]; __syncthreads(); }
    float sum = red[0];
    if (tid < NLOC) alpha[b * NLOC + tid] = e / sum;
}

__global__ void ctx_kernel(const float* __restrict__ feat, const float* __restrict__ alpha,
                           short* __restrict__ ctx_b) {
    int idx = blockIdx.x * blockDim.x + threadIdx.x;   // B*DV
    if (idx >= B * DV) return;
    int b = idx / DV, d = idx % DV;
    const float* p = feat + (size_t)b * NLOC * DV + d;
    const float* a = alpha + b * NLOC;
    float s = 0.f;
    for (int n = 0; n < NLOC; ++n) s += a[n] * p[(size_t)n * DV];
    ctx_b[idx] = (short)f2bf(s);
}

__global__ void emb_gather_kernel(const int* __restrict__ captions, const float* __restrict__ table,
                                  short* __restrict__ emb_b) {
    size_t idx = (size_t)blockIdx.x * blockDim.x + threadIdx.x;   // T*B*EMB
    if (idx >= (size_t)TT * B * EMB) return;
    int k = (int)(idx % EMB);
    int r = (int)(idx / EMB);      // r = t*B + b
    int t = r / B, b = r % B;
    int cap = captions[b * TT + t];
    emb_b[idx] = (short)f2bf(table[(size_t)cap * EMB + k]);
}

__global__ void f2bf_pad_kernel(const float* __restrict__ in, short* __restrict__ out,
                                size_t n, size_t npad) {
    size_t i = (size_t)blockIdx.x * blockDim.x + threadIdx.x;
    if (i >= npad) return;
    out[i] = (i < n) ? (short)f2bf(in[i]) : (short)0;
}

// W_hh [4096][1024] -> gate-interleaved rows P = u*4 + g (same buffer size)
__global__ void whh_perm_kernel(const float* __restrict__ in, short* __restrict__ out) {
    size_t idx = (size_t)blockIdx.x * blockDim.x + threadIdx.x;   // G4*HD
    if (idx >= (size_t)G4 * HD) return;
    int k = (int)(idx & (HD - 1));
    int P = (int)(idx >> 10);
    int u = P >> 2, g = P & 3;
    out[idx] = (short)f2bf(in[(size_t)(g * HD + u) * HD + k]);
}

__global__ void hcvt_kernel(const float* __restrict__ h, short* __restrict__ h_bf) {
    int idx = blockIdx.x * blockDim.x + threadIdx.x;   // B*HD
    if (idx >= B * HD) return;
    h_bf[idx] = (short)f2bf(h[idx]);
}

// ---------------- bf16 MFMA GEMM (proven, UNTOUCHED): C = A @ Bw^T ----------------
template<int BN, int WR, int WC>
__global__ __launch_bounds__(256)
void gemm_bf16(const short* __restrict__ A, const short* __restrict__ Bw,
               float* __restrict__ C,
               const float* __restrict__ bias0, const float* __restrict__ bias1,
               int M, int N, int K, int lda, int ldb, int ldc) {
    constexpr int BM = 128;
    constexpr int BK = 32;
    constexpr int WM = BM / WR;
    constexpr int WN = BN / WC;
    constexpr int FM = WM / 16;
    constexpr int FN = WN / 16;
    __shared__ __align__(16) short As[BM * BK];
    __shared__ __align__(16) short Bs[BN * BK];
    const int tid  = threadIdx.x;
    const int wave = tid >> 6, lane = tid & 63;
    const int wr = wave / WC, wc = wave % WC;
    const int m0 = blockIdx.y * BM, n0 = blockIdx.x * BN;
    const int laneoff = lane * 16;   // byte offset within wave segment

    f32x4 acc[FM][FN] = {};

    for (int k0 = 0; k0 < K; k0 += BK) {
        #pragma unroll
        for (int r = 0; r < 2; ++r) {
            int o   = r * 4096 + wave * 1024 + laneoff;  // byte offset in As
            int row = o >> 6;                            // 64 B per row
            int col = (o & 63) >> 1;
            gload_lds16(A + (size_t)(m0 + row) * lda + k0 + col,
                        (char*)As + r * 4096 + wave * 1024);
        }
        constexpr int BBYTES = BN * BK * 2;
        if constexpr (BBYTES >= 4096) {
            #pragma unroll
            for (int r = 0; r < BBYTES / 4096; ++r) {
                int o   = r * 4096 + wave * 1024 + laneoff;
                int row = o >> 6;
                int col = (o & 63) >> 1;
                gload_lds16(Bw + (size_t)(n0 + row) * ldb + k0 + col,
                            (char*)Bs + r * 4096 + wave * 1024);
            }
        } else {
            constexpr int NW = BBYTES / 1024;   // waves participating
            if (wave < NW) {
                int o   = wave * 1024 + laneoff;
                int row = o >> 6;
                int col = (o & 63) >> 1;
                gload_lds16(Bw + (size_t)(n0 + row) * ldb + k0 + col,
                            (char*)Bs + wave * 1024);
            }
        }
        __syncthreads();

        bf16x8 a[FM], b[FN];
        const int kfr = (lane >> 4) * 8;
        #pragma unroll
        for (int i = 0; i < FM; ++i) {
            int row = wr * WM + i * 16 + (lane & 15);
            a[i] = *(const bf16x8*)&As[row * BK + kfr];
        }
        #pragma unroll
        for (int j = 0; j < FN; ++j) {
            int row = wc * WN + j * 16 + (lane & 15);
            b[j] = *(const bf16x8*)&Bs[row * BK + kfr];
        }
        #pragma unroll
        for (int i = 0; i < FM; ++i)
            #pragma unroll
            for (int j = 0; j < FN; ++j)
                acc[i][j] = __builtin_amdgcn_mfma_f32_16x16x32_bf16(a[i], b[j], acc[i][j], 0, 0, 0);
        __syncthreads();
    }

    #pragma unroll
    for (int i = 0; i < FM; ++i) {
        #pragma unroll
        for (int j = 0; j < FN; ++j) {
            int col = n0 + wc * WN + j * 16 + (lane & 15);
            if (col >= N) continue;
            float bv = (bias0 ? bias0[col] : 0.f) + (bias1 ? bias1[col] : 0.f);
            #pragma unroll
            for (int q = 0; q < 4; ++q) {
                int row = m0 + wr * WM + i * 16 + (lane >> 4) * 4 + q;
                if (row < M) C[(size_t)row * ldc + col] = acc[i][j][q] + bv;
            }
        }
    }
}

// ---------------- persistent recurrence: ALL 20 steps in one cooperative kernel ----------------
// grid 256 blocks (1/CU) x 256 threads = 4 waves. Block b: nx = b&127 (32 P-rows =
// 8 units x 4 gates), my = b>>7 (64 batch rows). W slice staged into LDS ONCE and
// reused for all TT steps. Per step: {stage A half (64 rows x 512), barrier,
// 16 k-iters x 2 MFMA, barrier} x2, gsm exchange, fused LSTM elementwise (c held in
// REGISTERS across steps), grid.sync() (device-scope fence -> h visible cross-XCD).
// Swizzle (rule 21 both sides): granule g of row r holds global granule g^(r&7);
// reads apply the same involution -> <=2-way bank aliasing (free).
__global__ __launch_bounds__(256)
void lstm_persist(const short* __restrict__ H0, const short* __restrict__ Whh_p,
                  const float* __restrict__ gate_pre, const float* __restrict__ gctx,
                  const float* __restrict__ cbuf,
                  short* __restrict__ h_ping, short* __restrict__ h_pong,
                  short* __restrict__ Hall_b) {
    __shared__ __align__(16) short Ws[32 * 1024];   // 64 KB, resident across steps
    __shared__ __align__(16) short As[64 * 512];    // 64 KB, restaged per half-step
    __shared__ float gsm[4][64][8];                 // 8 KB
    cg::grid_group grid = cg::this_grid();

    const int tid  = threadIdx.x;
    const int lane = tid & 63, wave = tid >> 6;
    const int bid  = blockIdx.x;
    const int nx = bid & 127, my = bid >> 7;
    const int n0 = nx * 32;                         // P base (units nx*8..+7)
    const int m0 = my * 64;                         // batch base

    // ---- stage W slice ONCE: 32 rows x 128 granules = 4096 granules, 16 rounds ----
    #pragma unroll
    for (int it = 0; it < 16; ++it) {
        int fg  = it * 256 + tid;
        int row = fg >> 7;                          // 128 granules (2048 B) per row
        int g   = fg & 127;
        int col = (g ^ (row & 7)) * 8;
        gload_lds16(Whh_p + (size_t)(n0 + row) * HD + col,
                    (char*)Ws + it * 4096 + wave * 1024);
    }

    const int arowL = wave * 16 + (lane & 15);
    const int brow0 = lane & 15;
    const int brow1 = 16 + (lane & 15);
    const int kg    = lane >> 4;

    // ---- c in registers across all steps (this thread owns 2 fixed (r,u) pairs) ----
    const int m_a = tid >> 3,           u8_a = tid & 7;
    const int m_b = (tid + 256) >> 3,   u8_b = (tid + 256) & 7;
    const int r_a = m0 + m_a, u_a = nx * 8 + u8_a;
    const int r_b = m0 + m_b, u_b = nx * 8 + u8_b;
    float c_a = cbuf[(size_t)r_a * HD + u_a];
    float c_b = cbuf[(size_t)r_b * HD + u_b];

    for (int t = 0; t < TT; ++t) {
        const short* Hprev = (t == 0) ? H0 : ((t & 1) ? h_pong : h_ping);
        short* Hnext = (t & 1) ? h_ping : h_pong;
        const float* pre_t = gate_pre + (size_t)t * B * G4;
        f32x4 acc0 = {}, acc1 = {};

        #pragma unroll
        for (int h2 = 0; h2 < 2; ++h2) {
            const int k0 = h2 * 512;
            // stage A half: 64 rows x 64 granules = 4096 granules, 16 rounds
            #pragma unroll
            for (int it = 0; it < 16; ++it) {
                int fg  = it * 256 + tid;
                int row = fg >> 6;                  // 64 granules (1024 B) per row
                int g   = fg & 63;
                int col = (g ^ (row & 7)) * 8;
                gload_lds16(Hprev + (size_t)(m0 + row) * HD + k0 + col,
                            (char*)As + it * 4096 + wave * 1024);
            }
            __syncthreads();                        // drains W (t=0) + A stages
            #pragma unroll
            for (int ks = 0; ks < 16; ++ks) {
                int lgA = ks * 4 + kg;              // A: 64 granules/row
                int lgW = h2 * 64 + ks * 4 + kg;    // W: 128 granules/row (full K)
                bf16x8 a  = *(const bf16x8*)((const char*)As + arowL * 1024 + ((lgA ^ (arowL & 7)) << 4));
                bf16x8 w0 = *(const bf16x8*)((const char*)Ws + brow0 * 2048 + ((lgW ^ (brow0 & 7)) << 4));
                bf16x8 w1 = *(const bf16x8*)((const char*)Ws + brow1 * 2048 + ((lgW ^ (brow1 & 7)) << 4));
                acc0 = __builtin_amdgcn_mfma_f32_16x16x32_bf16(a, w0, acc0, 0, 0, 0);
                acc1 = __builtin_amdgcn_mfma_f32_16x16x32_bf16(a, w1, acc1, 0, 0, 0);
            }
            __syncthreads();                        // A reads done before restage
        }

        // scatter gates: tile0 p = brow0, tile1 p = brow1; unit p>>2, gate p&3
        #pragma unroll
        for (int q = 0; q < 4; ++q) {
            int rr = wave * 16 + (lane >> 4) * 4 + q;
            gsm[brow0 & 3][rr][brow0 >> 2] = acc0[q];
            gsm[brow1 & 3][rr][brow1 >> 2] = acc1[q];
        }
        __syncthreads();

        // fused LSTM elementwise: 2 fixed elems per thread, c in registers
        {
            size_t pb = (size_t)r_a * G4 + u_a;
            float gi  = gsm[0][m_a][u8_a] + pre_t[pb]          + gctx[pb];
            float gf  = gsm[1][m_a][u8_a] + pre_t[pb + HD]     + gctx[pb + HD];
            float gg2 = gsm[2][m_a][u8_a] + pre_t[pb + 2 * HD] + gctx[pb + 2 * HD];
            float go  = gsm[3][m_a][u8_a] + pre_t[pb + 3 * HD] + gctx[pb + 3 * HD];
            float si = 1.f / (1.f + expf(-gi));
            float sf = 1.f / (1.f + expf(-gf));
            float so = 1.f / (1.f + expf(-go));
            c_a = sf * c_a + si * tanhf(gg2);
            float hn = so * tanhf(c_a);
            short hb = (short)f2bf(hn);
            Hnext[(size_t)r_a * HD + u_a] = hb;
            Hall_b[(size_t)t * BH + (size_t)r_a * HD + u_a] = hb;
        }
        {
            size_t pb = (size_t)r_b * G4 + u_b;
            float gi  = gsm[0][m_b][u8_b] + pre_t[pb]          + gctx[pb];
            float gf  = gsm[1][m_b][u8_b] + pre_t[pb + HD]     + gctx[pb + HD];
            float gg2 = gsm[2][m_b][u8_b] + pre_t[pb + 2 * HD] + gctx[pb + 2 * HD];
            float go  = gsm[3][m_b][u8_b] + pre_t[pb + 3 * HD] + gctx[pb + 3 * HD];
            float si = 1.f / (1.f + expf(-gi));
            float sf = 1.f / (1.f + expf(-gf));
            float so = 1.f / (1.f + expf(-go));
            c_b = sf * c_b + si * tanhf(gg2);
            float hn = so * tanhf(c_b);
            short hb = (short)f2bf(hn);
            Hnext[(size_t)r_b * HD + u_b] = hb;
            Hall_b[(size_t)t * BH + (size_t)r_b * HD + u_b] = hb;
        }

        grid.sync();                                // h visible device-wide before next step
    }
}

// ---------------- single-pass LDS softmax: row (40 KB) staged once ----------------
__global__ __launch_bounds__(512)
void softmax_kernel(float* __restrict__ words_logout, float* __restrict__ smout) {
    __shared__ float rowbuf[VV];   // 40 KB
    __shared__ float red[512];
    int r = blockIdx.x;            // T*B rows
    int tid = threadIdx.x;         // 512
    float* row = words_logout + (size_t)r * VV;
    float m = -1e30f;
    for (int i = tid; i < VV; i += 512) {
        float v = row[i];
        rowbuf[i] = v;
        m = fmaxf(m, v);
    }
    red[tid] = m; __syncthreads();
    for (int s = 256; s > 0; s >>= 1) { if (tid < s) red[tid] = fmaxf(red[tid], red[tid + s]); __syncthreads(); }
    m = red[0]; __syncthreads();
    float sum = 0.f;
    for (int i = tid; i < VV; i += 512) sum += expf(rowbuf[i] - m);
    red[tid] = sum; __syncthreads();
    for (int s = 256; s > 0; s >>= 1) { if (tid < s) red[tid] += red[tid + s]; __syncthreads(); }
    sum = red[0];
    float inv = 1.f / sum;
    float lz = logf(sum);
    for (int i = tid; i < VV; i += 512) {
        float x = rowbuf[i];
        smout[(size_t)r * VV + i] = expf(x - m) * inv;
        row[i] = x - m - lz;
    }
}

// ---------------- launch ----------------
extern "C" void kernel_launch(void* const* d_in, const int* in_sizes, int n_in,
                              void* d_out, int out_size, void* d_ws, size_t ws_size,
                              hipStream_t stream) {
    const float* features    = (const float*)d_in[0];
    const int*   captions    = (const int*)  d_in[1];
    const float* W_init_h    = (const float*)d_in[2];
    const float* W_init_c    = (const float*)d_in[3];
    const float* W_attn_v    = (const float*)d_in[4];
    const float* b_attn_v    = (const float*)d_in[5];
    // d_in[6], d_in[7] (W_attn_h, b_attn_h) dead: softmax shift-invariance.
    const float* embed_table = (const float*)d_in[8];
    const float* W_ih        = (const float*)d_in[9];
    const float* W_hh        = (const float*)d_in[10];
    const float* b_ih        = (const float*)d_in[11];
    const float* b_hh        = (const float*)d_in[12];
    const float* W_out       = (const float*)d_in[13];
    const float* b_out       = (const float*)d_in[14];

    float* out   = (float*)d_out;
    float* words = out;                        // first half (log_softmax in place)
    float* s2    = out + (size_t)TT * B * VV;  // second half: scratch until final softmax

    // second-half scratch — byte-identical layout to the passing binary (FROZEN)
    float* gate_pre = s2;                                        // 10,485,760 f
    short* Hall_b   = (short*)(s2 + (size_t)10485760);           // TT x B*HD bf16
    short* Wout_b   = (short*)(s2 + (size_t)10485760 + 1310720); // VPAD*HD
    short* Wih_b    = Wout_b + (size_t)VPAD * HD;
    short* Whh_b    = Wih_b  + (size_t)G4 * HD;                  // PERMUTED W_hh
    short* Wini_h_b = Whh_b  + (size_t)G4 * HD;
    short* Wini_c_b = Wini_h_b + (size_t)HD * DV;

    // ws small scratch
    char* w = (char*)d_ws;
    size_t off = 0;
    auto alloc = [&](size_t bytes) { void* p = w + off; off = (off + bytes + 255) & ~255UL; return p; };
    float* attv   = (float*)alloc((size_t)B * NLOC * 4);
    float* alpha  = (float*)alloc((size_t)B * NLOC * 4);
    float* gctx   = (float*)alloc((size_t)B * G4 * 4);
    float* h0f    = (float*)alloc((size_t)B * HD * 4);
    float* cbuf   = (float*)alloc((size_t)B * HD * 4);
    short* fmean_b= (short*)alloc((size_t)B * DV * 2);
    short* ctx_b  = (short*)alloc((size_t)B * DV * 2);
    short* h_ping = (short*)alloc((size_t)B * HD * 2);
    short* h_pong = (short*)alloc((size_t)B * HD * 2);
    short* emb_b  = (short*)alloc((size_t)TT * B * EMB * 2);

    // ---- weight conversions (identical) ----
    f2bf_pad_kernel<<<((size_t)VPAD * HD + 255) / 256, 256, 0, stream>>>(
        W_out, Wout_b, (size_t)VV * HD, (size_t)VPAD * HD);
    f2bf_pad_kernel<<<((size_t)G4 * HD + 255) / 256, 256, 0, stream>>>(
        W_ih, Wih_b, (size_t)G4 * HD, (size_t)G4 * HD);
    whh_perm_kernel<<<((size_t)G4 * HD + 255) / 256, 256, 0, stream>>>(W_hh, Whh_b);
    f2bf_pad_kernel<<<((size_t)HD * DV + 255) / 256, 256, 0, stream>>>(
        W_init_h, Wini_h_b, (size_t)HD * DV, (size_t)HD * DV);
    f2bf_pad_kernel<<<((size_t)HD * DV + 255) / 256, 256, 0, stream>>>(
        W_init_c, Wini_c_b, (size_t)HD * DV, (size_t)HD * DV);

    // ---- phase 1: time-parallel (identical) ----
    fmean_kernel<<<(B * DV + 255) / 256, 256, 0, stream>>>(features, fmean_b);
    attv_kernel<<<B * NLOC, 64, 0, stream>>>(features, W_attn_v, b_attn_v, attv);
    alpha_kernel<<<B, 256, 0, stream>>>(attv, alpha);
    ctx_kernel<<<(B * DV + 255) / 256, 256, 0, stream>>>(features, alpha, ctx_b);
    emb_gather_kernel<<<((size_t)TT * B * EMB + 255) / 256, 256, 0, stream>>>(captions, embed_table, emb_b);

    // h0 / c0 (identical)
    gemm_bf16<32, 4, 1><<<dim3(HD / 32, 1), 256, 0, stream>>>(
        fmean_b, Wini_h_b, h0f, nullptr, nullptr, B, HD, DV, DV, DV, HD);
    gemm_bf16<32, 4, 1><<<dim3(HD / 32, 1), 256, 0, stream>>>(
        fmean_b, Wini_c_b, cbuf, nullptr, nullptr, B, HD, DV, DV, DV, HD);
    hcvt_kernel<<<(B * HD + 255) / 256, 256, 0, stream>>>(h0f, h_ping);

    // gctx / gate_pre (identical call-sites)
    gemm_bf16<32, 4, 1><<<dim3(G4 / 32, 1), 256, 0, stream>>>(
        ctx_b, Wih_b, gctx, b_ih, b_hh, B, G4, DV, DV, HD, G4);
    gemm_bf16<128, 2, 2><<<dim3(G4 / 128, TT * B / 128), 256, 0, stream>>>(
        emb_b, Wih_b + DV, gate_pre, nullptr, nullptr, TT * B, G4, EMB, EMB, DV + EMB, G4);

    // ---- phase 2: persistent cooperative recurrence (THE delta) ----
    {
        const short* H0 = h_ping;
        void* args[] = { (void*)&H0, (void*)&Whh_b, (void*)&gate_pre, (void*)&gctx,
                         (void*)&cbuf, (void*)&h_ping, (void*)&h_pong, (void*)&Hall_b };
        hipLaunchCooperativeKernel((void*)lstm_persist, dim3(256), dim3(256),
                                   args, 0, stream);
    }

    // ---- phase 3: words = Hall @ W_out^T + b_out (identical GEMM + softmax) ----
    gemm_bf16<128, 2, 2><<<dim3(VPAD / 128, TT * B / 128), 256, 0, stream>>>(
        Hall_b, Wout_b, words, b_out, nullptr, TT * B, VV, HD, HD, HD, VV);
    softmax_kernel<<<TT * B, 512, 0, stream>>>(words, s2);
}

// Round 13
// 519.930 us; speedup vs baseline: 2.0511x; 2.0511x over previous
//
#include <hip/hip_runtime.h>
#include <math.h>

#define B    128
#define NLOC 196
#define DV   512
#define EMB  512
#define HD   1024
#define VV   10000
#define TT   20
#define G4   4096   // 4*HD
#define VPAD 10112  // 79*128
#define BH   (B*HD)

typedef short bf16x8 __attribute__((ext_vector_type(8)));
typedef float f32x4  __attribute__((ext_vector_type(4)));

__device__ __forceinline__ unsigned short f2bf(float x) {
    unsigned u = __builtin_bit_cast(unsigned, x);
    unsigned r = (u + 0x7fffu + ((u >> 16) & 1u)) >> 16;
    return (unsigned short)r;
}

__device__ __forceinline__ void gload_lds16(const void* g, void* lds) {
    __builtin_amdgcn_global_load_lds(
        (const __attribute__((address_space(1))) void*)g,
        (__attribute__((address_space(3))) void*)lds, 16, 0, 0);
}

// ---------------- small kernels ----------------

__global__ void fmean_kernel(const float* __restrict__ feat, short* __restrict__ fmean_b) {
    int idx = blockIdx.x * blockDim.x + threadIdx.x;   // B*DV
    if (idx >= B * DV) return;
    int b = idx / DV, d = idx % DV;
    const float* p = feat + (size_t)b * NLOC * DV + d;
    float s = 0.f;
    for (int n = 0; n < NLOC; ++n) s += p[(size_t)n * DV];
    fmean_b[idx] = (short)f2bf(s * (1.0f / NLOC));
}

__global__ void attv_kernel(const float* __restrict__ feat, const float* __restrict__ wv,
                            const float* __restrict__ bv, float* __restrict__ attv) {
    int row  = blockIdx.x;         // B*NLOC
    int lane = threadIdx.x;        // 64
    const float* p = feat + (size_t)row * DV;
    float s = 0.f;
    for (int k = lane; k < DV; k += 64) s += p[k] * wv[k];
    for (int off = 32; off > 0; off >>= 1) s += __shfl_down(s, off);
    if (lane == 0) attv[row] = s + bv[0];
}

__global__ void alpha_kernel(const float* __restrict__ attv, float* __restrict__ alpha) {
    int b   = blockIdx.x;          // B
    int tid = threadIdx.x;         // 256
    __shared__ float red[256];
    float v = (tid < NLOC) ? attv[b * NLOC + tid] : -1e30f;
    red[tid] = v; __syncthreads();
    for (int s = 128; s > 0; s >>= 1) { if (tid < s) red[tid] = fmaxf(red[tid], red[tid + s]); __syncthreads(); }
    float m = red[0]; __syncthreads();
    float e = (tid < NLOC) ? expf(v - m) : 0.f;
    red[tid] = e; __syncthreads();
    for (int s = 128; s > 0; s >>= 1) { if (tid < s) red[tid] += red[tid + s]; __syncthreads(); }
    float sum = red[0];
    if (tid < NLOC) alpha[b * NLOC + tid] = e / sum;
}

__global__ void ctx_kernel(const float* __restrict__ feat, const float* __restrict__ alpha,
                           short* __restrict__ ctx_b) {
    int idx = blockIdx.x * blockDim.x + threadIdx.x;   // B*DV
    if (idx >= B * DV) return;
    int b = idx / DV, d = idx % DV;
    const float* p = feat + (size_t)b * NLOC * DV + d;
    const float* a = alpha + b * NLOC;
    float s = 0.f;
    for (int n = 0; n < NLOC; ++n) s += a[n] * p[(size_t)n * DV];
    ctx_b[idx] = (short)f2bf(s);
}

__global__ void emb_gather_kernel(const int* __restrict__ captions, const float* __restrict__ table,
                                  short* __restrict__ emb_b) {
    size_t idx = (size_t)blockIdx.x * blockDim.x + threadIdx.x;   // T*B*EMB
    if (idx >= (size_t)TT * B * EMB) return;
    int k = (int)(idx % EMB);
    int r = (int)(idx / EMB);      // r = t*B + b
    int t = r / B, b = r % B;
    int cap = captions[b * TT + t];
    emb_b[idx] = (short)f2bf(table[(size_t)cap * EMB + k]);
}

__global__ void f2bf_pad_kernel(const float* __restrict__ in, short* __restrict__ out,
                                size_t n, size_t npad) {
    size_t i = (size_t)blockIdx.x * blockDim.x + threadIdx.x;
    if (i >= npad) return;
    out[i] = (i < n) ? (short)f2bf(in[i]) : (short)0;
}

// W_hh [4096][1024] -> gate-interleaved rows P = u*4 + g (same buffer size)
__global__ void whh_perm_kernel(const float* __restrict__ in, short* __restrict__ out) {
    size_t idx = (size_t)blockIdx.x * blockDim.x + threadIdx.x;   // G4*HD
    if (idx >= (size_t)G4 * HD) return;
    int k = (int)(idx & (HD - 1));
    int P = (int)(idx >> 10);
    int u = P >> 2, g = P & 3;
    out[idx] = (short)f2bf(in[(size_t)(g * HD + u) * HD + k]);
}

__global__ void hcvt_kernel(const float* __restrict__ h, short* __restrict__ h_bf) {
    int idx = blockIdx.x * blockDim.x + threadIdx.x;   // B*HD
    if (idx >= B * HD) return;
    h_bf[idx] = (short)f2bf(h[idx]);
}

// ---------------- bf16 MFMA GEMM (proven, UNTOUCHED): C = A @ Bw^T ----------------
template<int BN, int WR, int WC>
__global__ __launch_bounds__(256)
void gemm_bf16(const short* __restrict__ A, const short* __restrict__ Bw,
               float* __restrict__ C,
               const float* __restrict__ bias0, const float* __restrict__ bias1,
               int M, int N, int K, int lda, int ldb, int ldc) {
    constexpr int BM = 128;
    constexpr int BK = 32;
    constexpr int WM = BM / WR;
    constexpr int WN = BN / WC;
    constexpr int FM = WM / 16;
    constexpr int FN = WN / 16;
    __shared__ __align__(16) short As[BM * BK];
    __shared__ __align__(16) short Bs[BN * BK];
    const int tid  = threadIdx.x;
    const int wave = tid >> 6, lane = tid & 63;
    const int wr = wave / WC, wc = wave % WC;
    const int m0 = blockIdx.y * BM, n0 = blockIdx.x * BN;
    const int laneoff = lane * 16;   // byte offset within wave segment

    f32x4 acc[FM][FN] = {};

    for (int k0 = 0; k0 < K; k0 += BK) {
        #pragma unroll
        for (int r = 0; r < 2; ++r) {
            int o   = r * 4096 + wave * 1024 + laneoff;  // byte offset in As
            int row = o >> 6;                            // 64 B per row
            int col = (o & 63) >> 1;
            gload_lds16(A + (size_t)(m0 + row) * lda + k0 + col,
                        (char*)As + r * 4096 + wave * 1024);
        }
        constexpr int BBYTES = BN * BK * 2;
        if constexpr (BBYTES >= 4096) {
            #pragma unroll
            for (int r = 0; r < BBYTES / 4096; ++r) {
                int o   = r * 4096 + wave * 1024 + laneoff;
                int row = o >> 6;
                int col = (o & 63) >> 1;
                gload_lds16(Bw + (size_t)(n0 + row) * ldb + k0 + col,
                            (char*)Bs + r * 4096 + wave * 1024);
            }
        } else {
            constexpr int NW = BBYTES / 1024;   // waves participating
            if (wave < NW) {
                int o   = wave * 1024 + laneoff;
                int row = o >> 6;
                int col = (o & 63) >> 1;
                gload_lds16(Bw + (size_t)(n0 + row) * ldb + k0 + col,
                            (char*)Bs + wave * 1024);
            }
        }
        __syncthreads();

        bf16x8 a[FM], b[FN];
        const int kfr = (lane >> 4) * 8;
        #pragma unroll
        for (int i = 0; i < FM; ++i) {
            int row = wr * WM + i * 16 + (lane & 15);
            a[i] = *(const bf16x8*)&As[row * BK + kfr];
        }
        #pragma unroll
        for (int j = 0; j < FN; ++j) {
            int row = wc * WN + j * 16 + (lane & 15);
            b[j] = *(const bf16x8*)&Bs[row * BK + kfr];
        }
        #pragma unroll
        for (int i = 0; i < FM; ++i)
            #pragma unroll
            for (int j = 0; j < FN; ++j)
                acc[i][j] = __builtin_amdgcn_mfma_f32_16x16x32_bf16(a[i], b[j], acc[i][j], 0, 0, 0);
        __syncthreads();
    }

    #pragma unroll
    for (int i = 0; i < FM; ++i) {
        #pragma unroll
        for (int j = 0; j < FN; ++j) {
            int col = n0 + wc * WN + j * 16 + (lane & 15);
            if (col >= N) continue;
            float bv = (bias0 ? bias0[col] : 0.f) + (bias1 ? bias1[col] : 0.f);
            #pragma unroll
            for (int q = 0; q < 4; ++q) {
                int row = m0 + wr * WM + i * 16 + (lane >> 4) * 4 + q;
                if (row < M) C[(size_t)row * ldc + col] = acc[i][j][q] + bv;
            }
        }
    }
}

// ---------------- fused recurrence step v7: quarter-K double-buffered pipeline ----------------
// grid (G4/32 = 128, B/64 = 2) = 256 blocks = 1/CU. 256 threads = 4 waves.
// Block: 64 batch rows x 32 P-rows (8 units x 4 gates), K = 4 quarters of 256.
// LDS: A dbuf 2x32 KB + W dbuf 2x16 KB + gsm 8 KB = 104 KB -> 1 block/CU.
// Pipeline: stage q0; sync; loop q: {issue stage q+1 into idle buf, compute q, sync}.
// 3 of 4 stage phases fly under compute (v6 exposed both serially).
// Swizzle (rule 21 both sides): granule g of row r holds global granule g^(r&7);
// frag reads apply the same involution -> 8 banks x 2 lanes = 2-way (free).
__global__ __launch_bounds__(256)
void lstm_step7(const short* __restrict__ Hprev, const short* __restrict__ Whh_p,
                const float* __restrict__ pre_t, const float* __restrict__ gctx,
                float* __restrict__ cbuf, short* __restrict__ Hnext,
                short* __restrict__ Hall_t) {
    __shared__ __align__(16) short As[2][64 * 256];   // 32 KB each
    __shared__ __align__(16) short Ws[2][32 * 256];   // 16 KB each
    __shared__ float gsm[4][64][8];                   // 8 KB
    const int tid  = threadIdx.x;
    const int lane = tid & 63, wave = tid >> 6;
    const int n0 = blockIdx.x * 32;                   // P base (units blockIdx.x*8..+7)
    const int m0 = blockIdx.y * 64;                   // batch base

    const int arowL = wave * 16 + (lane & 15);
    const int brow0 = lane & 15;
    const int brow1 = 16 + (lane & 15);
    const int kg    = lane >> 4;

    // stage quarter q into buffer buf (A: 2048 granules = 8 rounds; W: 1024 = 4 rounds)
    auto stageA = [&](int q, int buf) {
        const int k0 = q * 256;
        #pragma unroll
        for (int it = 0; it < 8; ++it) {
            int fg  = it * 256 + tid;
            int row = fg >> 5;                        // 32 granules (512 B) per row
            int g   = fg & 31;
            int col = (g ^ (row & 7)) * 8;            // pre-swizzled global elem col
            gload_lds16(Hprev + (size_t)(m0 + row) * HD + k0 + col,
                        (char*)As[buf] + it * 4096 + wave * 1024);
        }
    };
    auto stageW = [&](int q, int buf) {
        const int k0 = q * 256;
        #pragma unroll
        for (int it = 0; it < 4; ++it) {
            int fg  = it * 256 + tid;
            int row = fg >> 5;
            int g   = fg & 31;
            int col = (g ^ (row & 7)) * 8;
            gload_lds16(Whh_p + (size_t)(n0 + row) * HD + k0 + col,
                        (char*)Ws[buf] + it * 4096 + wave * 1024);
        }
    };

    f32x4 acc0 = {}, acc1 = {};

    stageA(0, 0); stageW(0, 0);
    __syncthreads();

    #pragma unroll
    for (int q = 0; q < 4; ++q) {
        const int cur = q & 1;
        if (q + 1 < 4) { stageA(q + 1, cur ^ 1); stageW(q + 1, cur ^ 1); }
        #pragma unroll
        for (int ks = 0; ks < 8; ++ks) {
            int lg = ks * 4 + kg;                     // logical granule 0..31
            bf16x8 a  = *(const bf16x8*)((const char*)As[cur] + arowL * 512 + ((lg ^ (arowL & 7)) << 4));
            bf16x8 w0 = *(const bf16x8*)((const char*)Ws[cur] + brow0 * 512 + ((lg ^ (brow0 & 7)) << 4));
            bf16x8 w1 = *(const bf16x8*)((const char*)Ws[cur] + brow1 * 512 + ((lg ^ (brow1 & 7)) << 4));
            acc0 = __builtin_amdgcn_mfma_f32_16x16x32_bf16(a, w0, acc0, 0, 0, 0);
            acc1 = __builtin_amdgcn_mfma_f32_16x16x32_bf16(a, w1, acc1, 0, 0, 0);
        }
        __syncthreads();                              // next-buf staged + reads drained
    }

    // scatter gates: tile0 p = brow0, tile1 p = brow1; unit p>>2, gate p&3
    #pragma unroll
    for (int q = 0; q < 4; ++q) {
        int rr = wave * 16 + (lane >> 4) * 4 + q;
        gsm[brow0 & 3][rr][brow0 >> 2] = acc0[q];
        gsm[brow1 & 3][rr][brow1 >> 2] = acc1[q];
    }
    __syncthreads();

    // fused LSTM elementwise: 64 rows x 8 units = 512 elems, 2 per thread
    #pragma unroll
    for (int s = 0; s < 2; ++s) {
        int idx = tid + s * 256;
        int m = idx >> 3, u8 = idx & 7;
        int r = m0 + m, u = blockIdx.x * 8 + u8;
        size_t pb = (size_t)r * G4 + u;
        float gi  = gsm[0][m][u8] + pre_t[pb]          + gctx[pb];
        float gf  = gsm[1][m][u8] + pre_t[pb + HD]     + gctx[pb + HD];
        float gg2 = gsm[2][m][u8] + pre_t[pb + 2 * HD] + gctx[pb + 2 * HD];
        float go  = gsm[3][m][u8] + pre_t[pb + 3 * HD] + gctx[pb + 3 * HD];
        float si = 1.f / (1.f + expf(-gi));
        float sf = 1.f / (1.f + expf(-gf));
        float so = 1.f / (1.f + expf(-go));
        float cn = sf * cbuf[(size_t)r * HD + u] + si * tanhf(gg2);
        float hn = so * tanhf(cn);
        cbuf[(size_t)r * HD + u] = cn;
        short hb = (short)f2bf(hn);
        Hnext[(size_t)r * HD + u]  = hb;
        Hall_t[(size_t)r * HD + u] = hb;
    }
}

// ---------------- single-pass LDS softmax: row (40 KB) staged once ----------------
__global__ __launch_bounds__(512)
void softmax_kernel(float* __restrict__ words_logout, float* __restrict__ smout) {
    __shared__ float rowbuf[VV];   // 40 KB
    __shared__ float red[512];
    int r = blockIdx.x;            // T*B rows
    int tid = threadIdx.x;         // 512
    float* row = words_logout + (size_t)r * VV;
    float m = -1e30f;
    for (int i = tid; i < VV; i += 512) {
        float v = row[i];
        rowbuf[i] = v;
        m = fmaxf(m, v);
    }
    red[tid] = m; __syncthreads();
    for (int s = 256; s > 0; s >>= 1) { if (tid < s) red[tid] = fmaxf(red[tid], red[tid + s]); __syncthreads(); }
    m = red[0]; __syncthreads();
    float sum = 0.f;
    for (int i = tid; i < VV; i += 512) sum += expf(rowbuf[i] - m);
    red[tid] = sum; __syncthreads();
    for (int s = 256; s > 0; s >>= 1) { if (tid < s) red[tid] += red[tid + s]; __syncthreads(); }
    sum = red[0];
    float inv = 1.f / sum;
    float lz = logf(sum);
    for (int i = tid; i < VV; i += 512) {
        float x = rowbuf[i];
        smout[(size_t)r * VV + i] = expf(x - m) * inv;
        row[i] = x - m - lz;
    }
}

// ---------------- launch ----------------
extern "C" void kernel_launch(void* const* d_in, const int* in_sizes, int n_in,
                              void* d_out, int out_size, void* d_ws, size_t ws_size,
                              hipStream_t stream) {
    const float* features    = (const float*)d_in[0];
    const int*   captions    = (const int*)  d_in[1];
    const float* W_init_h    = (const float*)d_in[2];
    const float* W_init_c    = (const float*)d_in[3];
    const float* W_attn_v    = (const float*)d_in[4];
    const float* b_attn_v    = (const float*)d_in[5];
    // d_in[6], d_in[7] (W_attn_h, b_attn_h) dead: softmax shift-invariance.
    const float* embed_table = (const float*)d_in[8];
    const float* W_ih        = (const float*)d_in[9];
    const float* W_hh        = (const float*)d_in[10];
    const float* b_ih        = (const float*)d_in[11];
    const float* b_hh        = (const float*)d_in[12];
    const float* W_out       = (const float*)d_in[13];
    const float* b_out       = (const float*)d_in[14];

    float* out   = (float*)d_out;
    float* words = out;                        // first half (log_softmax in place)
    float* s2    = out + (size_t)TT * B * VV;  // second half: scratch until final softmax

    // second-half scratch — byte-identical layout to the passing binary (FROZEN)
    float* gate_pre = s2;                                        // 10,485,760 f
    short* Hall_b   = (short*)(s2 + (size_t)10485760);           // TT x B*HD bf16
    short* Wout_b   = (short*)(s2 + (size_t)10485760 + 1310720); // VPAD*HD
    short* Wih_b    = Wout_b + (size_t)VPAD * HD;
    short* Whh_b    = Wih_b  + (size_t)G4 * HD;                  // PERMUTED W_hh
    short* Wini_h_b = Whh_b  + (size_t)G4 * HD;
    short* Wini_c_b = Wini_h_b + (size_t)HD * DV;

    // ws small scratch
    char* w = (char*)d_ws;
    size_t off = 0;
    auto alloc = [&](size_t bytes) { void* p = w + off; off = (off + bytes + 255) & ~255UL; return p; };
    float* attv   = (float*)alloc((size_t)B * NLOC * 4);
    float* alpha  = (float*)alloc((size_t)B * NLOC * 4);
    float* gctx   = (float*)alloc((size_t)B * G4 * 4);
    float* h0f    = (float*)alloc((size_t)B * HD * 4);
    float* cbuf   = (float*)alloc((size_t)B * HD * 4);
    short* fmean_b= (short*)alloc((size_t)B * DV * 2);
    short* ctx_b  = (short*)alloc((size_t)B * DV * 2);
    short* h_ping = (short*)alloc((size_t)B * HD * 2);
    short* h_pong = (short*)alloc((size_t)B * HD * 2);
    short* emb_b  = (short*)alloc((size_t)TT * B * EMB * 2);

    // ---- weight conversions (identical) ----
    f2bf_pad_kernel<<<((size_t)VPAD * HD + 255) / 256, 256, 0, stream>>>(
        W_out, Wout_b, (size_t)VV * HD, (size_t)VPAD * HD);
    f2bf_pad_kernel<<<((size_t)G4 * HD + 255) / 256, 256, 0, stream>>>(
        W_ih, Wih_b, (size_t)G4 * HD, (size_t)G4 * HD);
    whh_perm_kernel<<<((size_t)G4 * HD + 255) / 256, 256, 0, stream>>>(W_hh, Whh_b);
    f2bf_pad_kernel<<<((size_t)HD * DV + 255) / 256, 256, 0, stream>>>(
        W_init_h, Wini_h_b, (size_t)HD * DV, (size_t)HD * DV);
    f2bf_pad_kernel<<<((size_t)HD * DV + 255) / 256, 256, 0, stream>>>(
        W_init_c, Wini_c_b, (size_t)HD * DV, (size_t)HD * DV);

    // ---- phase 1: time-parallel (identical) ----
    fmean_kernel<<<(B * DV + 255) / 256, 256, 0, stream>>>(features, fmean_b);
    attv_kernel<<<B * NLOC, 64, 0, stream>>>(features, W_attn_v, b_attn_v, attv);
    alpha_kernel<<<B, 256, 0, stream>>>(attv, alpha);
    ctx_kernel<<<(B * DV + 255) / 256, 256, 0, stream>>>(features, alpha, ctx_b);
    emb_gather_kernel<<<((size_t)TT * B * EMB + 255) / 256, 256, 0, stream>>>(captions, embed_table, emb_b);

    // h0 / c0 (identical)
    gemm_bf16<32, 4, 1><<<dim3(HD / 32, 1), 256, 0, stream>>>(
        fmean_b, Wini_h_b, h0f, nullptr, nullptr, B, HD, DV, DV, DV, HD);
    gemm_bf16<32, 4, 1><<<dim3(HD / 32, 1), 256, 0, stream>>>(
        fmean_b, Wini_c_b, cbuf, nullptr, nullptr, B, HD, DV, DV, DV, HD);
    hcvt_kernel<<<(B * HD + 255) / 256, 256, 0, stream>>>(h0f, h_ping);

    // gctx / gate_pre (identical call-sites)
    gemm_bf16<32, 4, 1><<<dim3(G4 / 32, 1), 256, 0, stream>>>(
        ctx_b, Wih_b, gctx, b_ih, b_hh, B, G4, DV, DV, HD, G4);
    gemm_bf16<128, 2, 2><<<dim3(G4 / 128, TT * B / 128), 256, 0, stream>>>(
        emb_b, Wih_b + DV, gate_pre, nullptr, nullptr, TT * B, G4, EMB, EMB, DV + EMB, G4);

    // ---- phase 2: fused recurrence (v7 pipelined step kernel — THE delta) ----
    for (int t = 0; t < TT; ++t) {
        lstm_step7<<<dim3(G4 / 32, B / 64), 256, 0, stream>>>(
            (t & 1) ? h_pong : h_ping, Whh_b, gate_pre + (size_t)t * B * G4, gctx,
            cbuf, (t & 1) ? h_ping : h_pong, Hall_b + (size_t)t * BH);
    }

    // ---- phase 3: words = Hall @ W_out^T + b_out (identical GEMM + softmax) ----
    gemm_bf16<128, 2, 2><<<dim3(VPAD / 128, TT * B / 128), 256, 0, stream>>>(
        Hall_b, Wout_b, words, b_out, nullptr, TT * B, VV, HD, HD, HD, VV);
    softmax_kernel<<<TT * B, 512, 0, stream>>>(words, s2);
}

// Round 14
// 488.417 us; speedup vs baseline: 2.1834x; 1.0645x over previous
//
#include <hip/hip_runtime.h>
#include <math.h>

#define B    128
#define NLOC 196
#define DV   512
#define EMB  512
#define HD   1024
#define VV   10000
#define TT   20
#define G4   4096   // 4*HD
#define VPAD 10112  // 79*128
#define BH   (B*HD)

typedef short bf16x8 __attribute__((ext_vector_type(8)));
typedef float f32x4  __attribute__((ext_vector_type(4)));

__device__ __forceinline__ unsigned short f2bf(float x) {
    unsigned u = __builtin_bit_cast(unsigned, x);
    unsigned r = (u + 0x7fffu + ((u >> 16) & 1u)) >> 16;
    return (unsigned short)r;
}

__device__ __forceinline__ void gload_lds16(const void* g, void* lds) {
    __builtin_amdgcn_global_load_lds(
        (const __attribute__((address_space(1))) void*)g,
        (__attribute__((address_space(3))) void*)lds, 16, 0, 0);
}

// ---------------- small kernels ----------------

__global__ void fmean_kernel(const float* __restrict__ feat, short* __restrict__ fmean_b) {
    int idx = blockIdx.x * blockDim.x + threadIdx.x;   // B*DV
    if (idx >= B * DV) return;
    int b = idx / DV, d = idx % DV;
    const float* p = feat + (size_t)b * NLOC * DV + d;
    float s = 0.f;
    for (int n = 0; n < NLOC; ++n) s += p[(size_t)n * DV];
    fmean_b[idx] = (short)f2bf(s * (1.0f / NLOC));
}

__global__ void attv_kernel(const float* __restrict__ feat, const float* __restrict__ wv,
                            const float* __restrict__ bv, float* __restrict__ attv) {
    int row  = blockIdx.x;         // B*NLOC
    int lane = threadIdx.x;        // 64
    const float* p = feat + (size_t)row * DV;
    float s = 0.f;
    for (int k = lane; k < DV; k += 64) s += p[k] * wv[k];
    for (int off = 32; off > 0; off >>= 1) s += __shfl_down(s, off);
    if (lane == 0) attv[row] = s + bv[0];
}

__global__ void alpha_kernel(const float* __restrict__ attv, float* __restrict__ alpha) {
    int b   = blockIdx.x;          // B
    int tid = threadIdx.x;         // 256
    __shared__ float red[256];
    float v = (tid < NLOC) ? attv[b * NLOC + tid] : -1e30f;
    red[tid] = v; __syncthreads();
    for (int s = 128; s > 0; s >>= 1) { if (tid < s) red[tid] = fmaxf(red[tid], red[tid + s]); __syncthreads(); }
    float m = red[0]; __syncthreads();
    float e = (tid < NLOC) ? expf(v - m) : 0.f;
    red[tid] = e; __syncthreads();
    for (int s = 128; s > 0; s >>= 1) { if (tid < s) red[tid] += red[tid + s]; __syncthreads(); }
    float sum = red[0];
    if (tid < NLOC) alpha[b * NLOC + tid] = e / sum;
}

__global__ void ctx_kernel(const float* __restrict__ feat, const float* __restrict__ alpha,
                           short* __restrict__ ctx_b) {
    int idx = blockIdx.x * blockDim.x + threadIdx.x;   // B*DV
    if (idx >= B * DV) return;
    int b = idx / DV, d = idx % DV;
    const float* p = feat + (size_t)b * NLOC * DV + d;
    const float* a = alpha + b * NLOC;
    float s = 0.f;
    for (int n = 0; n < NLOC; ++n) s += a[n] * p[(size_t)n * DV];
    ctx_b[idx] = (short)f2bf(s);
}

__global__ void emb_gather_kernel(const int* __restrict__ captions, const float* __restrict__ table,
                                  short* __restrict__ emb_b) {
    size_t idx = (size_t)blockIdx.x * blockDim.x + threadIdx.x;   // T*B*EMB
    if (idx >= (size_t)TT * B * EMB) return;
    int k = (int)(idx % EMB);
    int r = (int)(idx / EMB);      // r = t*B + b
    int t = r / B, b = r % B;
    int cap = captions[b * TT + t];
    emb_b[idx] = (short)f2bf(table[(size_t)cap * EMB + k]);
}

__global__ void f2bf_pad_kernel(const float* __restrict__ in, short* __restrict__ out,
                                size_t n, size_t npad) {
    size_t i = (size_t)blockIdx.x * blockDim.x + threadIdx.x;
    if (i >= npad) return;
    out[i] = (i < n) ? (short)f2bf(in[i]) : (short)0;
}

// W_hh [4096][1024] -> gate-interleaved rows P = u*4 + g (same buffer size)
__global__ void whh_perm_kernel(const float* __restrict__ in, short* __restrict__ out) {
    size_t idx = (size_t)blockIdx.x * blockDim.x + threadIdx.x;   // G4*HD
    if (idx >= (size_t)G4 * HD) return;
    int k = (int)(idx & (HD - 1));
    int P = (int)(idx >> 10);
    int u = P >> 2, g = P & 3;
    out[idx] = (short)f2bf(in[(size_t)(g * HD + u) * HD + k]);
}

__global__ void hcvt_kernel(const float* __restrict__ h, short* __restrict__ h_bf) {
    int idx = blockIdx.x * blockDim.x + threadIdx.x;   // B*HD
    if (idx >= B * HD) return;
    h_bf[idx] = (short)f2bf(h[idx]);
}

// ---------------- bf16 MFMA GEMM with conflict-free granule swizzle ----------------
// C[M,N] = A[M,K] @ Bw[N,K]^T. Same structure as the proven kernel; ONLY change:
// LDS slot granule s of row r holds global granule s ^ ((r>>1)&3) (rule 21 both
// sides: pre-swizzled global source col + same involution on frag reads).
// Per 16-lane phase: start-bank = (row&1)*16 + g'*4, distinct over 8 rows -> 2
// dwords/bank = BW minimum, conflict-free (was 8-way).
template<int BN, int WR, int WC>
__global__ __launch_bounds__(256)
void gemm_bf16(const short* __restrict__ A, const short* __restrict__ Bw,
               float* __restrict__ C,
               const float* __restrict__ bias0, const float* __restrict__ bias1,
               int M, int N, int K, int lda, int ldb, int ldc) {
    constexpr int BM = 128;
    constexpr int BK = 32;
    constexpr int WM = BM / WR;
    constexpr int WN = BN / WC;
    constexpr int FM = WM / 16;
    constexpr int FN = WN / 16;
    __shared__ __align__(16) short As[BM * BK];
    __shared__ __align__(16) short Bs[BN * BK];
    const int tid  = threadIdx.x;
    const int wave = tid >> 6, lane = tid & 63;
    const int wr = wave / WC, wc = wave % WC;
    const int m0 = blockIdx.y * BM, n0 = blockIdx.x * BN;
    const int laneoff = lane * 16;   // byte offset within wave segment

    f32x4 acc[FM][FN] = {};

    for (int k0 = 0; k0 < K; k0 += BK) {
        #pragma unroll
        for (int r = 0; r < 2; ++r) {
            int o   = r * 4096 + wave * 1024 + laneoff;  // byte offset in As
            int row = o >> 6;                            // 64 B per row
            int gr  = (o >> 4) & 3;                      // LDS slot granule
            int col = ((gr ^ ((row >> 1) & 3)) << 3);    // swizzled global elem col
            gload_lds16(A + (size_t)(m0 + row) * lda + k0 + col,
                        (char*)As + r * 4096 + wave * 1024);
        }
        constexpr int BBYTES = BN * BK * 2;
        if constexpr (BBYTES >= 4096) {
            #pragma unroll
            for (int r = 0; r < BBYTES / 4096; ++r) {
                int o   = r * 4096 + wave * 1024 + laneoff;
                int row = o >> 6;
                int gr  = (o >> 4) & 3;
                int col = ((gr ^ ((row >> 1) & 3)) << 3);
                gload_lds16(Bw + (size_t)(n0 + row) * ldb + k0 + col,
                            (char*)Bs + r * 4096 + wave * 1024);
            }
        } else {
            constexpr int NW = BBYTES / 1024;   // waves participating
            if (wave < NW) {
                int o   = wave * 1024 + laneoff;
                int row = o >> 6;
                int gr  = (o >> 4) & 3;
                int col = ((gr ^ ((row >> 1) & 3)) << 3);
                gload_lds16(Bw + (size_t)(n0 + row) * ldb + k0 + col,
                            (char*)Bs + wave * 1024);
            }
        }
        __syncthreads();

        bf16x8 a[FM], b[FN];
        const int kfrg = lane >> 4;                      // logical k-granule 0..3
        #pragma unroll
        for (int i = 0; i < FM; ++i) {
            int row = wr * WM + i * 16 + (lane & 15);
            a[i] = *(const bf16x8*)&As[row * BK + ((kfrg ^ ((row >> 1) & 3)) << 3)];
        }
        #pragma unroll
        for (int j = 0; j < FN; ++j) {
            int row = wc * WN + j * 16 + (lane & 15);
            b[j] = *(const bf16x8*)&Bs[row * BK + ((kfrg ^ ((row >> 1) & 3)) << 3)];
        }
        #pragma unroll
        for (int i = 0; i < FM; ++i)
            #pragma unroll
            for (int j = 0; j < FN; ++j)
                acc[i][j] = __builtin_amdgcn_mfma_f32_16x16x32_bf16(a[i], b[j], acc[i][j], 0, 0, 0);
        __syncthreads();
    }

    #pragma unroll
    for (int i = 0; i < FM; ++i) {
        #pragma unroll
        for (int j = 0; j < FN; ++j) {
            int col = n0 + wc * WN + j * 16 + (lane & 15);
            if (col >= N) continue;
            float bv = (bias0 ? bias0[col] : 0.f) + (bias1 ? bias1[col] : 0.f);
            #pragma unroll
            for (int q = 0; q < 4; ++q) {
                int row = m0 + wr * WM + i * 16 + (lane >> 4) * 4 + q;
                if (row < M) C[(size_t)row * ldc + col] = acc[i][j][q] + bv;
            }
        }
    }
}

// ---------------- fused recurrence step v6 (round-11 proven, 493 us): ONE block-round ----------------
__global__ __launch_bounds__(256)
void lstm_step6(const short* __restrict__ Hprev, const short* __restrict__ Whh_p,
                const float* __restrict__ pre_t, const float* __restrict__ gctx,
                float* __restrict__ cbuf, short* __restrict__ Hnext,
                short* __restrict__ Hall_t) {
    __shared__ __align__(16) short As[64 * 512];    // 64 KB (half-K)
    __shared__ __align__(16) short Ws[32 * 512];    // 32 KB (half-K)
    __shared__ float gsm[4][64][8];                 // 8 KB
    const int tid  = threadIdx.x;
    const int lane = tid & 63, wave = tid >> 6;
    const int n0 = blockIdx.x * 32;                 // P base (units blockIdx.x*8..+7)
    const int m0 = blockIdx.y * 64;                 // batch base

    const int arowL = wave * 16 + (lane & 15);      // this wave's A row in LDS
    const int brow0 = lane & 15;                    // P tile 0 row
    const int brow1 = 16 + (lane & 15);             // P tile 1 row
    const int kg    = lane >> 4;

    f32x4 acc0 = {}, acc1 = {};

    for (int h2 = 0; h2 < 2; ++h2) {
        const int k0 = h2 * 512;
        #pragma unroll
        for (int it = 0; it < 16; ++it) {
            int fg  = it * 256 + tid;
            int row = fg >> 6;                      // 64 granules (1024 B) per row
            int g   = fg & 63;
            int col = (g ^ (row & 7)) * 8;          // pre-swizzled global elem col
            gload_lds16(Hprev + (size_t)(m0 + row) * HD + k0 + col,
                        (char*)As + it * 4096 + wave * 1024);
        }
        #pragma unroll
        for (int it = 0; it < 8; ++it) {
            int fg  = it * 256 + tid;
            int row = fg >> 6;
            int g   = fg & 63;
            int col = (g ^ (row & 7)) * 8;
            gload_lds16(Whh_p + (size_t)(n0 + row) * HD + k0 + col,
                        (char*)Ws + it * 4096 + wave * 1024);
        }
        __syncthreads();
        #pragma unroll
        for (int ks = 0; ks < 16; ++ks) {
            int lg = ks * 4 + kg;                   // logical granule 0..63
            bf16x8 a  = *(const bf16x8*)((const char*)As + arowL * 1024 + ((lg ^ (arowL & 7)) << 4));
            bf16x8 w0 = *(const bf16x8*)((const char*)Ws + brow0 * 1024 + ((lg ^ (brow0 & 7)) << 4));
            bf16x8 w1 = *(const bf16x8*)((const char*)Ws + brow1 * 1024 + ((lg ^ (brow1 & 7)) << 4));
            acc0 = __builtin_amdgcn_mfma_f32_16x16x32_bf16(a, w0, acc0, 0, 0, 0);
            acc1 = __builtin_amdgcn_mfma_f32_16x16x32_bf16(a, w1, acc1, 0, 0, 0);
        }
        __syncthreads();
    }

    #pragma unroll
    for (int q = 0; q < 4; ++q) {
        int rr = wave * 16 + (lane >> 4) * 4 + q;
        gsm[brow0 & 3][rr][brow0 >> 2] = acc0[q];
        gsm[brow1 & 3][rr][brow1 >> 2] = acc1[q];
    }
    __syncthreads();

    #pragma unroll
    for (int s = 0; s < 2; ++s) {
        int idx = tid + s * 256;
        int m = idx >> 3, u8 = idx & 7;
        int r = m0 + m, u = blockIdx.x * 8 + u8;
        size_t pb = (size_t)r * G4 + u;
        float gi  = gsm[0][m][u8] + pre_t[pb]          + gctx[pb];
        float gf  = gsm[1][m][u8] + pre_t[pb + HD]     + gctx[pb + HD];
        float gg2 = gsm[2][m][u8] + pre_t[pb + 2 * HD] + gctx[pb + 2 * HD];
        float go  = gsm[3][m][u8] + pre_t[pb + 3 * HD] + gctx[pb + 3 * HD];
        float si = 1.f / (1.f + expf(-gi));
        float sf = 1.f / (1.f + expf(-gf));
        float so = 1.f / (1.f + expf(-go));
        float cn = sf * cbuf[(size_t)r * HD + u] + si * tanhf(gg2);
        float hn = so * tanhf(cn);
        cbuf[(size_t)r * HD + u] = cn;
        short hb = (short)f2bf(hn);
        Hnext[(size_t)r * HD + u]  = hb;
        Hall_t[(size_t)r * HD + u] = hb;
    }
}

// ---------------- single-pass LDS softmax: row (40 KB) staged once ----------------
__global__ __launch_bounds__(512)
void softmax_kernel(float* __restrict__ words_logout, float* __restrict__ smout) {
    __shared__ float rowbuf[VV];   // 40 KB
    __shared__ float red[512];
    int r = blockIdx.x;            // T*B rows
    int tid = threadIdx.x;         // 512
    float* row = words_logout + (size_t)r * VV;
    float m = -1e30f;
    for (int i = tid; i < VV; i += 512) {
        float v = row[i];
        rowbuf[i] = v;
        m = fmaxf(m, v);
    }
    red[tid] = m; __syncthreads();
    for (int s = 256; s > 0; s >>= 1) { if (tid < s) red[tid] = fmaxf(red[tid], red[tid + s]); __syncthreads(); }
    m = red[0]; __syncthreads();
    float sum = 0.f;
    for (int i = tid; i < VV; i += 512) sum += expf(rowbuf[i] - m);
    red[tid] = sum; __syncthreads();
    for (int s = 256; s > 0; s >>= 1) { if (tid < s) red[tid] += red[tid + s]; __syncthreads(); }
    sum = red[0];
    float inv = 1.f / sum;
    float lz = logf(sum);
    for (int i = tid; i < VV; i += 512) {
        float x = rowbuf[i];
        smout[(size_t)r * VV + i] = expf(x - m) * inv;
        row[i] = x - m - lz;
    }
}

// ---------------- launch ----------------
extern "C" void kernel_launch(void* const* d_in, const int* in_sizes, int n_in,
                              void* d_out, int out_size, void* d_ws, size_t ws_size,
                              hipStream_t stream) {
    const float* features    = (const float*)d_in[0];
    const int*   captions    = (const int*)  d_in[1];
    const float* W_init_h    = (const float*)d_in[2];
    const float* W_init_c    = (const float*)d_in[3];
    const float* W_attn_v    = (const float*)d_in[4];
    const float* b_attn_v    = (const float*)d_in[5];
    // d_in[6], d_in[7] (W_attn_h, b_attn_h) dead: softmax shift-invariance.
    const float* embed_table = (const float*)d_in[8];
    const float* W_ih        = (const float*)d_in[9];
    const float* W_hh        = (const float*)d_in[10];
    const float* b_ih        = (const float*)d_in[11];
    const float* b_hh        = (const float*)d_in[12];
    const float* W_out       = (const float*)d_in[13];
    const float* b_out       = (const float*)d_in[14];

    float* out   = (float*)d_out;
    float* words = out;                        // first half (log_softmax in place)
    float* s2    = out + (size_t)TT * B * VV;  // second half: scratch until final softmax

    // second-half scratch — byte-identical layout to the passing binary (FROZEN)
    float* gate_pre = s2;                                        // 10,485,760 f
    short* Hall_b   = (short*)(s2 + (size_t)10485760);           // TT x B*HD bf16
    short* Wout_b   = (short*)(s2 + (size_t)10485760 + 1310720); // VPAD*HD
    short* Wih_b    = Wout_b + (size_t)VPAD * HD;
    short* Whh_b    = Wih_b  + (size_t)G4 * HD;                  // PERMUTED W_hh
    short* Wini_h_b = Whh_b  + (size_t)G4 * HD;
    short* Wini_c_b = Wini_h_b + (size_t)HD * DV;

    // ws small scratch
    char* w = (char*)d_ws;
    size_t off = 0;
    auto alloc = [&](size_t bytes) { void* p = w + off; off = (off + bytes + 255) & ~255UL; return p; };
    float* attv   = (float*)alloc((size_t)B * NLOC * 4);
    float* alpha  = (float*)alloc((size_t)B * NLOC * 4);
    float* gctx   = (float*)alloc((size_t)B * G4 * 4);
    float* h0f    = (float*)alloc((size_t)B * HD * 4);
    float* cbuf   = (float*)alloc((size_t)B * HD * 4);
    short* fmean_b= (short*)alloc((size_t)B * DV * 2);
    short* ctx_b  = (short*)alloc((size_t)B * DV * 2);
    short* h_ping = (short*)alloc((size_t)B * HD * 2);
    short* h_pong = (short*)alloc((size_t)B * HD * 2);
    short* emb_b  = (short*)alloc((size_t)TT * B * EMB * 2);

    // ---- weight conversions (identical) ----
    f2bf_pad_kernel<<<((size_t)VPAD * HD + 255) / 256, 256, 0, stream>>>(
        W_out, Wout_b, (size_t)VV * HD, (size_t)VPAD * HD);
    f2bf_pad_kernel<<<((size_t)G4 * HD + 255) / 256, 256, 0, stream>>>(
        W_ih, Wih_b, (size_t)G4 * HD, (size_t)G4 * HD);
    whh_perm_kernel<<<((size_t)G4 * HD + 255) / 256, 256, 0, stream>>>(W_hh, Whh_b);
    f2bf_pad_kernel<<<((size_t)HD * DV + 255) / 256, 256, 0, stream>>>(
        W_init_h, Wini_h_b, (size_t)HD * DV, (size_t)HD * DV);
    f2bf_pad_kernel<<<((size_t)HD * DV + 255) / 256, 256, 0, stream>>>(
        W_init_c, Wini_c_b, (size_t)HD * DV, (size_t)HD * DV);

    // ---- phase 1: time-parallel (identical) ----
    fmean_kernel<<<(B * DV + 255) / 256, 256, 0, stream>>>(features, fmean_b);
    attv_kernel<<<B * NLOC, 64, 0, stream>>>(features, W_attn_v, b_attn_v, attv);
    alpha_kernel<<<B, 256, 0, stream>>>(attv, alpha);
    ctx_kernel<<<(B * DV + 255) / 256, 256, 0, stream>>>(features, alpha, ctx_b);
    emb_gather_kernel<<<((size_t)TT * B * EMB + 255) / 256, 256, 0, stream>>>(captions, embed_table, emb_b);

    // h0 / c0 (identical)
    gemm_bf16<32, 4, 1><<<dim3(HD / 32, 1), 256, 0, stream>>>(
        fmean_b, Wini_h_b, h0f, nullptr, nullptr, B, HD, DV, DV, DV, HD);
    gemm_bf16<32, 4, 1><<<dim3(HD / 32, 1), 256, 0, stream>>>(
        fmean_b, Wini_c_b, cbuf, nullptr, nullptr, B, HD, DV, DV, DV, HD);
    hcvt_kernel<<<(B * HD + 255) / 256, 256, 0, stream>>>(h0f, h_ping);

    // gctx / gate_pre (identical call-sites)
    gemm_bf16<32, 4, 1><<<dim3(G4 / 32, 1), 256, 0, stream>>>(
        ctx_b, Wih_b, gctx, b_ih, b_hh, B, G4, DV, DV, HD, G4);
    gemm_bf16<128, 2, 2><<<dim3(G4 / 128, TT * B / 128), 256, 0, stream>>>(
        emb_b, Wih_b + DV, gate_pre, nullptr, nullptr, TT * B, G4, EMB, EMB, DV + EMB, G4);

    // ---- phase 2: fused recurrence (v6 step kernel, round-11 proven) ----
    for (int t = 0; t < TT; ++t) {
        lstm_step6<<<dim3(G4 / 32, B / 64), 256, 0, stream>>>(
            (t & 1) ? h_pong : h_ping, Whh_b, gate_pre + (size_t)t * B * G4, gctx,
            cbuf, (t & 1) ? h_ping : h_pong, Hall_b + (size_t)t * BH);
    }

    // ---- phase 3: words = Hall @ W_out^T + b_out (swizzled GEMM + LDS softmax) ----
    gemm_bf16<128, 2, 2><<<dim3(VPAD / 128, TT * B / 128), 256, 0, stream>>>(
        Hall_b, Wout_b, words, b_out, nullptr, TT * B, VV, HD, HD, HD, VV);
    softmax_kernel<<<TT * B, 512, 0, stream>>>(words, s2);
}